// Round 7
// baseline (495.989 us; speedup 1.0000x reference)
//
#include <hip/hip_runtime.h>
#include <hip/hip_bf16.h>
#include <cstdint>
#include <cstddef>

using u16 = unsigned short;
using u32 = unsigned int;
using u64 = unsigned long long;

typedef __attribute__((ext_vector_type(8))) __bf16 bf16x8;
typedef __attribute__((ext_vector_type(4))) float f32x4;
typedef __attribute__((ext_vector_type(2))) float f32x2;
typedef __attribute__((ext_vector_type(4))) u32 u32x4;

typedef const __attribute__((address_space(1))) void* gas_ptr;
typedef __attribute__((address_space(3))) void* las_ptr;

__device__ __forceinline__ void async_cp16(const void* g, void* l) {
  __builtin_amdgcn_global_load_lds((gas_ptr)g, (las_ptr)l, 16, 0, 0);
}

__device__ __forceinline__ float bf2f(u16 u) {
  u32 v = ((u32)u) << 16;
  return __builtin_bit_cast(float, v);
}
__device__ __forceinline__ u16 f2bf(float f) {
  u32 v = __builtin_bit_cast(u32, f);
  u32 r = (v + 0x7fffu + ((v >> 16) & 1u)) >> 16;  // RNE
  return (u16)r;
}

__device__ __forceinline__ f32x4 mfma16(bf16x8 a, bf16x8 b, f32x4 c) {
  return __builtin_amdgcn_mfma_f32_16x16x32_bf16(a, b, c, 0, 0, 0);
}

// fused convert for x, wq, wk, wv (all independent, pre-QKV-gemm)
__global__ __launch_bounds__(256) void cvt4(const float* __restrict__ x,
                                            const float* __restrict__ wq,
                                            const float* __restrict__ wk,
                                            const float* __restrict__ wv,
                                            u16* __restrict__ xb,
                                            u16* __restrict__ wqkv) {
  const int B0 = 1048576;            // x: 2048*4096/8
  const int B1 = B0 + 2097152;       // wq: 4096*4096/8
  const int B2 = B1 + 524288;        // wk: 1024*4096/8
  const int B3 = B2 + 524288;        // wv
  int i = blockIdx.x * blockDim.x + threadIdx.x;
  int stride = gridDim.x * blockDim.x;
  for (; i < B3; i += stride) {
    const float* src; u16* dst; int j;
    if (i < B0)      { src = x;  dst = xb;                           j = i; }
    else if (i < B1) { src = wq; dst = wqkv;                         j = i - B0; }
    else if (i < B2) { src = wk; dst = wqkv + (size_t)4096 * 4096;   j = i - B1; }
    else             { src = wv; dst = wqkv + (size_t)5120 * 4096;   j = i - B2; }
    const float4* p = (const float4*)(src + (size_t)j * 8);
    float4 a = p[0], b = p[1];
    union { u16 us[8]; u32x4 v; } o;
    o.us[0] = f2bf(a.x); o.us[1] = f2bf(a.y); o.us[2] = f2bf(a.z); o.us[3] = f2bf(a.w);
    o.us[4] = f2bf(b.x); o.us[5] = f2bf(b.y); o.us[6] = f2bf(b.z); o.us[7] = f2bf(b.w);
    *(u32x4*)(dst + (size_t)j * 8) = o.v;
  }
}

// ---------------------------------------------------------------- QKV GEMM 256x256 v2
// BM=BN=256, BK=64, 512 threads (8 waves: wr in {0,1} x wc in {0..3}); per-wave
// output 128x64 = acc[8][4]. LDS: per buffer per matrix [256 rows][64 cols] bf16
// (128B rows, 8x16B segs, seg ^= row&7 — the PROVEN zero-conflict layout of the
// 128x128 kernel; R6's 32-col rows caused 9.4M bank conflicts). Double-buffered
// = 128KB -> 1 block/CU. Pipeline: consumer-staged halves (wave (wr,wc) stages
// A-half wr + B-half wc>>1, 8 cp16/tile), issue tile t+1's 8 loads then
// vmcnt(8) -> tile t landed, t+1 stays in flight the whole tile. Then 4 phases:
// {ds_read 4-8 frags; lgkmcnt(0)+sched_barrier; setprio(1); 16 MFMA;
// setprio(0); s_barrier} for role diversity between the 2 waves/SIMD.
// Epilogue: fused RoPE+RMSNorm (Q/K) / V-transpose (correctness-proven in R6).
__global__ __launch_bounds__(512, 2) void gemm256(const u16* __restrict__ A,
                                                  const u16* __restrict__ B,
                                                  int M, int N, int K,
                                                  u16* __restrict__ qh,
                                                  u16* __restrict__ khh,
                                                  u16* __restrict__ vt,
                                                  const float* __restrict__ freqs) {
  __shared__ __align__(16) u16 As[2][16384];
  __shared__ __align__(16) u16 Bs[2][16384];
  const int tid = threadIdx.x;
  const int wave = tid >> 6, lane = tid & 63;
  const int quad = lane >> 4, c16 = lane & 15;
  const int wr = wave >> 2, wc = wave & 3;

  const int mb = M >> 8;           // 8
  const int nb = N >> 8;           // 24
  const int per_xcd_n = nb >> 3;   // 3
  const int xcd = blockIdx.x & 7, lid = blockIdx.x >> 3;
  const int m_t = lid % mb, n_local = lid / mb;
  const int m0 = m_t * 256, n0 = (xcd * per_xcd_n + n_local) * 256;

  const u16* Ab = A + (size_t)m0 * K;
  const u16* Bb = B + (size_t)n0 * K;

  f32x4 acc[8][4] = {};

  // consumer-staging: wave (wr,wc) stages A-half wr and B-half bh=wc>>1.
  const int atg = wc * 64 + lane;                      // 0..255 within wr-group
  const int bh = wc >> 1;
  const int btg = (((wr << 1) | (wc & 1)) << 6) + lane;  // 0..255 within bh-group

  auto stage_tile = [&](int k0, int b) __attribute__((always_inline)) {
#pragma unroll
    for (int j = 0; j < 4; ++j) {
      int idx = atg + 256 * j;            // 0..1023 covers [128 rows][8 segs]
      int rl = idx >> 3;
      int row = wr * 128 + rl;
      int sg = (idx & 7) ^ (row & 7);
      async_cp16(Ab + (size_t)row * K + k0 + sg * 8, &As[b][wr * 8192 + idx * 8]);
    }
#pragma unroll
    for (int j = 0; j < 4; ++j) {
      int idx = btg + 256 * j;
      int rl = idx >> 3;
      int row = bh * 128 + rl;
      int sg = (idx & 7) ^ (row & 7);
      async_cp16(Bb + (size_t)row * K + k0 + sg * 8, &Bs[b][bh * 8192 + idx * 8]);
    }
  };

  bf16x8 bfr[4];
  auto phase = [&](int b, int ks, int mh, bool loadB) __attribute__((always_inline)) {
    bf16x8 af[4];
    if (loadB) {
#pragma unroll
      for (int nt = 0; nt < 4; ++nt) {
        int row = wc * 64 + nt * 16 + c16;
        bfr[nt] = *(const bf16x8*)(&Bs[b][row * 64 + (((ks * 4 + quad) ^ (row & 7)) * 8)]);
      }
    }
#pragma unroll
    for (int mt = 0; mt < 4; ++mt) {
      int row = wr * 128 + (mh * 4 + mt) * 16 + c16;
      af[mt] = *(const bf16x8*)(&As[b][row * 64 + (((ks * 4 + quad) ^ (row & 7)) * 8)]);
    }
    asm volatile("s_waitcnt lgkmcnt(0)" ::: "memory");
    __builtin_amdgcn_sched_barrier(0);
    __builtin_amdgcn_s_setprio(1);
#pragma unroll
    for (int mt = 0; mt < 4; ++mt)
#pragma unroll
      for (int nt = 0; nt < 4; ++nt)
        acc[mh * 4 + mt][nt] = mfma16(af[mt], bfr[nt], acc[mh * 4 + mt][nt]);
    __builtin_amdgcn_s_setprio(0);
    __builtin_amdgcn_s_barrier();
  };

  const int nk = K >> 6;  // 64
  stage_tile(0, 0);

#pragma unroll 1
  for (int t = 0; t < nk; ++t) {
    const int b = t & 1;
    const int k0 = t << 6;
    // issue next tile's 8 loads, then wait for THIS tile's 8 (counted vmcnt):
    if (t + 1 < nk) {
      stage_tile(k0 + 64, b ^ 1);
      asm volatile("s_waitcnt vmcnt(8)" ::: "memory");
    } else {
      asm volatile("s_waitcnt vmcnt(0)" ::: "memory");
    }
    __builtin_amdgcn_s_barrier();
    phase(b, 0, 0, true);
    phase(b, 0, 1, false);
    phase(b, 1, 0, true);
    phase(b, 1, 1, false);
  }

  // ---------------- fused QKV epilogue ----------------
  __syncthreads();  // full drain once; reuse As as f32 scratch
  float* sums = (float*)&As[0][0];  // [4 wc][256 rows]
  if (n0 < 5120) {
    // Q or K: RoPE (pairs = adjacent lanes) + RMSNorm over 128 (wave pair wc^1)
    float ss_arr[8][4];
    const int dbase = (wc & 1) * 64;
#pragma unroll
    for (int mt = 0; mt < 8; ++mt) {
#pragma unroll
      for (int r = 0; r < 4; ++r) {
        int s = m0 + wr * 128 + mt * 16 + quad * 4 + r;
        const float* fb = freqs + (size_t)s * 128;
        float ssv = 0.0f;
#pragma unroll
        for (int nt = 0; nt < 4; ++nt) {
          int d = dbase + nt * 16 + c16;
          float v = acc[mt][nt][r];
          float p = __shfl_xor(v, 1, 64);
          f32x2 ff = *(const f32x2*)(fb + (d & ~1));
          float res = (c16 & 1) ? fmaf(v, ff.x, p * ff.y)
                                : fmaf(v, ff.x, -p * ff.y);
          acc[mt][nt][r] = res;
          ssv = fmaf(res, res, ssv);
        }
#pragma unroll
        for (int m = 1; m < 16; m <<= 1) ssv += __shfl_xor(ssv, m, 64);
        ss_arr[mt][r] = ssv;
      }
    }
    if (c16 == 0) {
#pragma unroll
      for (int mt = 0; mt < 8; ++mt)
#pragma unroll
        for (int r = 0; r < 4; ++r)
          sums[wc * 256 + wr * 128 + mt * 16 + quad * 4 + r] = ss_arr[mt][r];
    }
    __syncthreads();
    const int head_col = n0 + wc * 64;
    u16* outb = (head_col < 4096)
                    ? (qh + (size_t)(head_col >> 7) * M * 128)
                    : (khh + (size_t)((head_col - 4096) >> 7) * M * 128);
#pragma unroll
    for (int mt = 0; mt < 8; ++mt) {
#pragma unroll
      for (int r = 0; r < 4; ++r) {
        int rl = wr * 128 + mt * 16 + quad * 4 + r;
        float tot = ss_arr[mt][r] + sums[(wc ^ 1) * 256 + rl];
        float scl = rsqrtf(tot * (1.0f / 128.0f) + 1e-5f);
        int s = m0 + rl;
#pragma unroll
        for (int nt = 0; nt < 4; ++nt)
          outb[(size_t)s * 128 + dbase + nt * 16 + c16] = f2bf(acc[mt][nt][r] * scl);
      }
    }
  } else {
    // V: store transposed vt[dv][s], 4 consecutive s packed per u64 store
#pragma unroll
    for (int mt = 0; mt < 8; ++mt) {
#pragma unroll
      for (int nt = 0; nt < 4; ++nt) {
        int dv = (n0 - 5120) + wc * 64 + nt * 16 + c16;
        int s0 = m0 + wr * 128 + mt * 16 + quad * 4;
        union { u16 us[4]; u64 v; } pk;
#pragma unroll
        for (int r = 0; r < 4; ++r) pk.us[r] = f2bf(acc[mt][nt][r]);
        *(u64*)(vt + (size_t)dv * M + s0) = pk.v;
      }
    }
  }
}

// ---------------------------------------------------------------- out-proj GEMM
// Proven 128x128 async-staged kernel, f32 C output. (control)
__global__ __launch_bounds__(256, 3) void gemm_out(const u16* __restrict__ A,
                                                   const u16* __restrict__ B,
                                                   float* __restrict__ C,
                                                   int M, int N, int K) {
  __shared__ __align__(16) u16 As[128 * 64];
  __shared__ __align__(16) u16 Bs[128 * 64];
  const int tid = threadIdx.x;
  const int wave = tid >> 6, lane = tid & 63;
  const int quad = lane >> 4, c16 = lane & 15;

  const int mb = M >> 7, nb = N >> 7;
  const int per_xcd_n = nb >> 3;
  const int xcd = blockIdx.x & 7, lid = blockIdx.x >> 3;
  const int m_t = lid % mb, n_local = lid / mb;
  const int m0 = m_t * 128, n0 = (xcd * per_xcd_n + n_local) * 128;

  const int wm = (wave & 1) * 64, wn = (wave >> 1) * 64;

  f32x4 acc[4][4] = {};

  const u16* Ab = A + (size_t)m0 * K;
  const u16* Bb = B + (size_t)n0 * K;

  for (int k0 = 0; k0 < K; k0 += 64) {
    __syncthreads();
#pragma unroll
    for (int i = 0; i < 4; ++i) {
      int idx = tid + 256 * i;
      int row = idx >> 3, sg = (idx & 7) ^ (row & 7);
      async_cp16(Ab + (size_t)row * K + k0 + sg * 8, As + (size_t)idx * 8);
    }
#pragma unroll
    for (int i = 0; i < 4; ++i) {
      int idx = tid + 256 * i;
      int row = idx >> 3, sg = (idx & 7) ^ (row & 7);
      async_cp16(Bb + (size_t)row * K + k0 + sg * 8, Bs + (size_t)idx * 8);
    }
    asm volatile("s_waitcnt vmcnt(0)" ::: "memory");
    __syncthreads();

    bf16x8 af[4][2], bfr[4][2];
#pragma unroll
    for (int mt = 0; mt < 4; ++mt) {
      int row = wm + mt * 16 + c16;
#pragma unroll
      for (int c = 0; c < 2; ++c)
        af[mt][c] = *(const bf16x8*)(As + row * 64 + (((c * 4 + quad) ^ (row & 7)) * 8));
    }
#pragma unroll
    for (int nt = 0; nt < 4; ++nt) {
      int row = wn + nt * 16 + c16;
#pragma unroll
      for (int c = 0; c < 2; ++c)
        bfr[nt][c] = *(const bf16x8*)(Bs + row * 64 + (((c * 4 + quad) ^ (row & 7)) * 8));
    }
#pragma unroll
    for (int c = 0; c < 2; ++c)
#pragma unroll
      for (int mt = 0; mt < 4; ++mt)
#pragma unroll
        for (int nt = 0; nt < 4; ++nt)
          acc[mt][nt] = mfma16(af[mt][c], bfr[nt][c], acc[mt][nt]);
  }

#pragma unroll
  for (int mt = 0; mt < 4; ++mt) {
#pragma unroll
    for (int nt = 0; nt < 4; ++nt) {
#pragma unroll
      for (int r = 0; r < 4; ++r) {
        int gm = m0 + wm + mt * 16 + quad * 4 + r;
        int gn = n0 + wn + nt * 16 + c16;
        C[(size_t)gm * N + gn] = acc[mt][nt][r];
      }
    }
  }
}

// ---------------------------------------------------------------- flash attention
// R5 version: 256 blocks x 512 threads, wave-groups on tile pair {15-p, p},
// shared K/V staging stream, + slack-proportional wo->bf16 conversion tail.
#define SEQ 2048
__global__ __launch_bounds__(512, 2) void attn(const u16* __restrict__ Q,
                                               const u16* __restrict__ Kh,
                                               const u16* __restrict__ VT,
                                               u16* __restrict__ O,
                                               const float* __restrict__ wo,
                                               u16* __restrict__ wob) {
  __shared__ __align__(16) u16 Ks[2][64 * 128];
  __shared__ __align__(16) u16 Vs[2][128 * 64];
  __shared__ __align__(16) u16 Ps[8][32 * 64];
  const int tid = threadIdx.x;
  const int wave = tid >> 6, lane = tid & 63;
  const int quad = lane >> 4, c16 = lane & 15;
  const int bid = blockIdx.x;
  const int hk = bid & 7;        // kv-head pinned to one XCD's L2
  const int rest = bid >> 3;
  const int hq = rest & 3;
  const int p = rest >> 2;       // 0..7
  const int h = hk * 4 + hq;

  const int wl = wave & 3, grp = wave >> 2;
  const int qt = grp ? p : (15 - p);        // grp0 = far tile, grp1 = near tile
  const int q0w = qt * 128 + wl * 32;
  const int kend = (15 - p) * 128 + 128;    // block-uniform (covers far tile)

  const float sc = 0.12751743f;  // log2(e)/sqrt(128)
  const float B = 16.5f;
  const u16* Kb = Kh + (size_t)hk * SEQ * 128;
  const u16* Vb = VT + (size_t)hk * 128 * SEQ;

  auto stage = [&](int t0, int b) __attribute__((always_inline)) {
#pragma unroll
    for (int i = 0; i < 2; ++i) {
      int idx = tid + 512 * i;
      int row = idx >> 4, sg = (idx & 15) ^ (row & 7);
      async_cp16(Kb + (size_t)(t0 + row) * 128 + sg * 8, &Ks[b][(size_t)idx * 8]);
    }
#pragma unroll
    for (int i = 0; i < 2; ++i) {
      int idx = tid + 512 * i;
      int row = idx >> 3, sg = (idx & 7) ^ (row & 7);
      async_cp16(Vb + (size_t)row * SEQ + t0 + sg * 8, &Vs[b][(size_t)idx * 8]);
    }
  };

  bf16x8 qfr[2][4];
  const u16* qbase = Q + (size_t)h * SEQ * 128;
#pragma unroll
  for (int g = 0; g < 2; ++g)
#pragma unroll
    for (int c = 0; c < 4; ++c)
      qfr[g][c] =
          *(const bf16x8*)(qbase + (size_t)(q0w + g * 16 + c16) * 128 + c * 32 + quad * 8);

  f32x4 o_acc[2][8] = {};
  float lsum[2][4] = {};

  stage(0, 0);

#pragma unroll 1
  for (int t0 = 0; t0 < kend; t0 += 64) {
    const int cur = (t0 >> 6) & 1;
    asm volatile("s_waitcnt vmcnt(0)" ::: "memory");
    __syncthreads();
    if (t0 + 64 < kend) stage(t0 + 64, cur ^ 1);

    if (t0 < q0w + 32) {
      f32x4 sa[2][4] = {};
      __builtin_amdgcn_s_setprio(1);
#pragma unroll
      for (int ct = 0; ct < 4; ++ct) {
        int t = ct * 16 + c16;
        int tbase = t * 128;
        int tsw = t & 7;
#pragma unroll
        for (int c = 0; c < 4; ++c) {
          bf16x8 kf = *(const bf16x8*)(&Ks[cur][tbase + (((c * 4 + quad) ^ tsw) * 8)]);
          sa[0][ct] = mfma16(qfr[0][c], kf, sa[0][ct]);
          sa[1][ct] = mfma16(qfr[1][c], kf, sa[1][ct]);
        }
      }
      __builtin_amdgcn_s_setprio(0);

      const bool diag = (t0 + 64 > q0w);
      auto soft = [&](bool masked) __attribute__((always_inline)) {
#pragma unroll
        for (int g = 0; g < 2; ++g) {
#pragma unroll
          for (int r = 0; r < 4; ++r) {
            int row = g * 16 + quad * 4 + r;
            int row_q = q0w + row;
            int rbase = row * 64;
            int rsw = row & 7;
#pragma unroll
            for (int ct = 0; ct < 4; ++ct) {
              float s = sa[g][ct][r];
              float arg = fmaf(s, sc, -B);
              if (masked) {
                int t_idx = t0 + ct * 16 + c16;
                arg = (t_idx <= row_q) ? arg : -1.0e30f;
              }
              float pe = exp2f(arg);
              lsum[g][r] += pe;
              u32 pb = (__builtin_bit_cast(u32, pe) + 0x8000u) >> 16;
              Ps[wave][rbase + (((ct * 2 + (c16 >> 3)) ^ rsw) * 8) + (c16 & 7)] = (u16)pb;
            }
          }
        }
      };
      if (diag) soft(true); else soft(false);
      asm volatile("s_waitcnt lgkmcnt(0)" ::: "memory");

      __builtin_amdgcn_s_setprio(1);
#pragma unroll
      for (int tc = 0; tc < 2; ++tc) {
        bf16x8 pf[2];
#pragma unroll
        for (int g = 0; g < 2; ++g) {
          int prow = g * 16 + c16;
          pf[g] = *(const bf16x8*)(&Ps[wave][prow * 64 + (((tc * 4 + quad) ^ (prow & 7)) * 8)]);
        }
#pragma unroll
        for (int nt = 0; nt < 8; ++nt) {
          int dl = nt * 16 + c16;
          bf16x8 vf = *(const bf16x8*)(&Vs[cur][dl * 64 + (((tc * 4 + quad) ^ (dl & 7)) * 8)]);
          o_acc[0][nt] = mfma16(pf[0], vf, o_acc[0][nt]);
          o_acc[1][nt] = mfma16(pf[1], vf, o_acc[1][nt]);
        }
      }
      __builtin_amdgcn_s_setprio(0);
    }
  }

#pragma unroll
  for (int g = 0; g < 2; ++g) {
#pragma unroll
    for (int r = 0; r < 4; ++r) {
      float l = lsum[g][r];
#pragma unroll
      for (int m = 1; m < 16; m <<= 1) l += __shfl_xor(l, m, 64);
      float inv = 1.0f / l;
      int s_idx = q0w + g * 16 + quad * 4 + r;
      u16* ob = O + (size_t)s_idx * 4096 + (size_t)h * 128;
#pragma unroll
      for (int nt = 0; nt < 8; ++nt) ob[nt * 16 + c16] = f2bf(o_acc[g][nt][r] * inv);
    }
  }

  // ---- wo->bf16 conversion tail, weighted by p (slack-proportional) ----
  {
    const int UNIT = 2341;                       // 896*2341 >= 2097152
    const int N8 = 2097152;                      // 4096*4096/8
    int su = 16 * p * (p - 1) + (bid & 31) * p;  // prefix units
    int i = su * UNIT + tid;
    int end = su * UNIT + p * UNIT;
    if (end > N8) end = N8;
    for (; i < end; i += 512) {
      const float4* src = (const float4*)(wo + (size_t)i * 8);
      float4 a = src[0], b = src[1];
      union { u16 us[8]; u32x4 v; } o;
      o.us[0] = f2bf(a.x); o.us[1] = f2bf(a.y); o.us[2] = f2bf(a.z); o.us[3] = f2bf(a.w);
      o.us[4] = f2bf(b.x); o.us[5] = f2bf(b.y); o.us[6] = f2bf(b.z); o.us[7] = f2bf(b.w);
      *(u32x4*)(wob + (size_t)i * 8) = o.v;
    }
  }
}

// ---------------------------------------------------------------- launch
extern "C" void kernel_launch(void* const* d_in, const int* in_sizes, int n_in,
                              void* d_out, int out_size, void* d_ws, size_t ws_size,
                              hipStream_t stream) {
  const float* x  = (const float*)d_in[0];
  const float* wq = (const float*)d_in[1];
  const float* wk = (const float*)d_in[2];
  const float* wv = (const float*)d_in[3];
  const float* wo = (const float*)d_in[4];
  const float* fr = (const float*)d_in[5];
  float* out = (float*)d_out;

  const size_t S = 2048, D = 4096, KV = 1024, NQKV = D + 2 * KV;  // 6144
  u16* p = (u16*)d_ws;
  u16* xb   = p; p += S * D;
  u16* wqkv = p; p += NQKV * D;
  u16* qh   = p; p += S * D;
  u16* khh  = p; p += S * KV;
  u16* vt   = p; p += KV * S;
  u16* ob   = p; p += S * D;
  u16* wob = wqkv;  // wqkv dead after QKV gemm; attn writes it, out-proj reads it

  // fused convert of x, wq, wk, wv (one launch)
  cvt4<<<dim3(2048), dim3(256), 0, stream>>>(x, wq, wk, wv, xb, wqkv);

  // fused QKV GEMM (256x256, counted-vmcnt 4-phase) + RoPE/RMSNorm/V-transpose
  gemm256<<<dim3((S / 256) * (NQKV / 256)), dim3(512), 0, stream>>>(
      xb, wqkv, (int)S, (int)NQKV, (int)D, qh, khh, vt, fr);

  // attention + slack-scheduled wo conversion
  attn<<<dim3(256), dim3(512), 0, stream>>>(qh, khh, vt, ob, wo, wob);

  gemm_out<<<dim3((S / 128) * (D / 128)), dim3(256), 0, stream>>>(
      ob, wob, out, (int)S, (int)D, (int)D);
}

// Round 8
// 468.271 us; speedup vs baseline: 1.0592x; 1.0592x over previous
//
#include <hip/hip_runtime.h>
#include <hip/hip_bf16.h>
#include <cstdint>
#include <cstddef>

using u16 = unsigned short;
using u32 = unsigned int;
using u64 = unsigned long long;

typedef __attribute__((ext_vector_type(8))) __bf16 bf16x8;
typedef __attribute__((ext_vector_type(4))) float f32x4;
typedef __attribute__((ext_vector_type(2))) float f32x2;
typedef __attribute__((ext_vector_type(4))) u32 u32x4;

typedef const __attribute__((address_space(1))) void* gas_ptr;
typedef __attribute__((address_space(3))) void* las_ptr;

__device__ __forceinline__ void async_cp16(const void* g, void* l) {
  __builtin_amdgcn_global_load_lds((gas_ptr)g, (las_ptr)l, 16, 0, 0);
}

__device__ __forceinline__ float bf2f(u16 u) {
  u32 v = ((u32)u) << 16;
  return __builtin_bit_cast(float, v);
}
__device__ __forceinline__ u16 f2bf(float f) {
  u32 v = __builtin_bit_cast(u32, f);
  u32 r = (v + 0x7fffu + ((v >> 16) & 1u)) >> 16;  // RNE
  return (u16)r;
}

__device__ __forceinline__ f32x4 mfma16(bf16x8 a, bf16x8 b, f32x4 c) {
  return __builtin_amdgcn_mfma_f32_16x16x32_bf16(a, b, c, 0, 0, 0);
}

// fused convert for x, wq, wk, wv (all independent, pre-QKV-gemm)
__global__ __launch_bounds__(256) void cvt4(const float* __restrict__ x,
                                            const float* __restrict__ wq,
                                            const float* __restrict__ wk,
                                            const float* __restrict__ wv,
                                            u16* __restrict__ xb,
                                            u16* __restrict__ wqkv) {
  const int B0 = 1048576;            // x: 2048*4096/8
  const int B1 = B0 + 2097152;       // wq: 4096*4096/8
  const int B2 = B1 + 524288;        // wk: 1024*4096/8
  const int B3 = B2 + 524288;        // wv
  int i = blockIdx.x * blockDim.x + threadIdx.x;
  int stride = gridDim.x * blockDim.x;
  for (; i < B3; i += stride) {
    const float* src; u16* dst; int j;
    if (i < B0)      { src = x;  dst = xb;                           j = i; }
    else if (i < B1) { src = wq; dst = wqkv;                         j = i - B0; }
    else if (i < B2) { src = wk; dst = wqkv + (size_t)4096 * 4096;   j = i - B1; }
    else             { src = wv; dst = wqkv + (size_t)5120 * 4096;   j = i - B2; }
    const float4* p = (const float4*)(src + (size_t)j * 8);
    float4 a = p[0], b = p[1];
    union { u16 us[8]; u32x4 v; } o;
    o.us[0] = f2bf(a.x); o.us[1] = f2bf(a.y); o.us[2] = f2bf(a.z); o.us[3] = f2bf(a.w);
    o.us[4] = f2bf(b.x); o.us[5] = f2bf(b.y); o.us[6] = f2bf(b.z); o.us[7] = f2bf(b.w);
    *(u32x4*)(dst + (size_t)j * 8) = o.v;
  }
}

// ---------------------------------------------------------------- QKV GEMM 256x256 v3
// Faithful m201-style 8-phase schedule. BM=BN=256, BK=64, 512 thr, 8 waves
// (wr in {0,1} x wc in {0..3}), per-wave out 128x64 = acc[8][4].
// LDS: As[2][2][128*64], Bs[2][2][128*64] = 128KB (parity = tile&1, half).
// Per 2-K-tile iteration i (t0=2i buf0, t1=2i+1 buf1), 8 phases, each:
//   {ds_reads of one register subtile; stage 1 half-tile (2 cp16/thr);
//    [vmcnt(4) at P4/P8]; s_barrier; lgkmcnt(0); setprio(1); 16 MFMA;
//    setprio(0); s_barrier}
// B of a tile is fully consumed at its first phase (8 ds_reads -> 32 VGPR),
// freeing B-slots for restage one phase later. Stage map (hazard-verified):
//   P1: A0,A1(2i+1)  P2: B0(2i+2)  P3: B1(2i+2)  P5: A0(2i+2)
//   P6: A1(2i+2)     P7: B0(2i+3)  P8: B1(2i+3)
// vmcnt(4)@P4 lands stages <=P1 (A(2i+1) ready for P5; B(2i+1) from prev P7/P8);
// vmcnt(4)@P8 lands <=P6 (tile 2i+2 fully resident for next P1).
__global__ __launch_bounds__(512, 2) void gemm256(const u16* __restrict__ A,
                                                  const u16* __restrict__ B,
                                                  int M, int N, int K,
                                                  u16* __restrict__ qh,
                                                  u16* __restrict__ khh,
                                                  u16* __restrict__ vt,
                                                  const float* __restrict__ freqs) {
  __shared__ __align__(16) u16 As[2][2][8192];
  __shared__ __align__(16) u16 Bs[2][2][8192];
  const int tid = threadIdx.x;
  const int wave = tid >> 6, lane = tid & 63;
  const int quad = lane >> 4, c16 = lane & 15;
  const int wr = wave >> 2, wc = wave & 3;

  const int mb = M >> 8;           // 8
  const int nb = N >> 8;           // 24
  const int per_xcd_n = nb >> 3;   // 3
  const int xcd = blockIdx.x & 7, lid = blockIdx.x >> 3;
  const int m_t = lid % mb, n_local = lid / mb;
  const int m0 = m_t * 256, n0 = (xcd * per_xcd_n + n_local) * 256;

  const u16* Ab = A + (size_t)m0 * K;
  const u16* Bb = B + (size_t)n0 * K;

  f32x4 acc[8][4] = {};
  bf16x8 breg[2][4];

  auto stA = [&](int t, int h) __attribute__((always_inline)) {
#pragma unroll
    for (int j = 0; j < 2; ++j) {
      int idx = tid + 512 * j;  // 0..1023 covers 128 rows x 8 segs
      int rl = idx >> 3;
      int sg = (idx & 7) ^ (rl & 7);
      async_cp16(Ab + (size_t)(h * 128 + rl) * K + (t << 6) + sg * 8,
                 &As[t & 1][h][idx * 8]);
    }
  };
  auto stB = [&](int t, int h) __attribute__((always_inline)) {
#pragma unroll
    for (int j = 0; j < 2; ++j) {
      int idx = tid + 512 * j;
      int rl = idx >> 3;
      int sg = (idx & 7) ^ (rl & 7);
      async_cp16(Bb + (size_t)(h * 128 + rl) * K + (t << 6) + sg * 8,
                 &Bs[t & 1][h][idx * 8]);
    }
  };
  auto ldA = [&](bf16x8* a, int par, int mh, int ks) __attribute__((always_inline)) {
#pragma unroll
    for (int mt = 0; mt < 4; ++mt) {
      int rl = mh * 64 + mt * 16 + c16;
      a[mt] = *(const bf16x8*)(&As[par][wr][rl * 64 + (((ks * 4 + quad) ^ (rl & 7)) * 8)]);
    }
  };
  auto ldB = [&](int par) __attribute__((always_inline)) {
#pragma unroll
    for (int ks = 0; ks < 2; ++ks)
#pragma unroll
      for (int nt = 0; nt < 4; ++nt) {
        int rl = (wc & 1) * 64 + nt * 16 + c16;
        breg[ks][nt] =
            *(const bf16x8*)(&Bs[par][wc >> 1][rl * 64 + (((ks * 4 + quad) ^ (rl & 7)) * 8)]);
      }
  };
  auto mm = [&](bf16x8* a, int mh, int ks) __attribute__((always_inline)) {
    __builtin_amdgcn_s_setprio(1);
#pragma unroll
    for (int mt = 0; mt < 4; ++mt)
#pragma unroll
      for (int nt = 0; nt < 4; ++nt)
        acc[mh * 4 + mt][nt] = mfma16(a[mt], breg[ks][nt], acc[mh * 4 + mt][nt]);
    __builtin_amdgcn_s_setprio(0);
  };

#define BARX() asm volatile("s_barrier" ::: "memory")
#define LGKM0()                                        \
  asm volatile("s_waitcnt lgkmcnt(0)" ::: "memory");   \
  __builtin_amdgcn_sched_barrier(0)

  // prologue: tiles 0 and 1 fully staged
  stA(0, 0); stA(0, 1); stB(0, 0); stB(0, 1);
  stA(1, 0); stA(1, 1); stB(1, 0); stB(1, 1);
  asm volatile("s_waitcnt vmcnt(0)" ::: "memory");
  BARX();

#pragma unroll 1
  for (int i = 0; i < 32; ++i) {
    bf16x8 a[4];
    // ---- P1: B(t0) full + A(t0,mh0,ks0); stage A(2i+1) both halves
    ldB(0); ldA(a, 0, 0, 0);
    if (i >= 1) { stA(2 * i + 1, 0); stA(2 * i + 1, 1); }
    BARX(); LGKM0(); mm(a, 0, 0); BARX();
    // ---- P2
    ldA(a, 0, 1, 0);
    if (2 * i + 2 < 64) stB(2 * i + 2, 0);
    BARX(); LGKM0(); mm(a, 1, 0); BARX();
    // ---- P3
    ldA(a, 0, 0, 1);
    if (2 * i + 2 < 64) stB(2 * i + 2, 1);
    BARX(); LGKM0(); mm(a, 0, 1); BARX();
    // ---- P4 (counted wait)
    ldA(a, 0, 1, 1);
    if (i < 31) asm volatile("s_waitcnt vmcnt(4)" ::: "memory");
    else        asm volatile("s_waitcnt vmcnt(0)" ::: "memory");
    BARX(); LGKM0(); mm(a, 1, 1); BARX();
    // ---- P5: B(t1) full + A(t1,mh0,ks0); stage A0(2i+2)
    ldB(1); ldA(a, 1, 0, 0);
    if (2 * i + 2 < 64) stA(2 * i + 2, 0);
    BARX(); LGKM0(); mm(a, 0, 0); BARX();
    // ---- P6
    ldA(a, 1, 1, 0);
    if (2 * i + 2 < 64) stA(2 * i + 2, 1);
    BARX(); LGKM0(); mm(a, 1, 0); BARX();
    // ---- P7
    ldA(a, 1, 0, 1);
    if (2 * i + 3 < 64) stB(2 * i + 3, 0);
    BARX(); LGKM0(); mm(a, 0, 1); BARX();
    // ---- P8 (counted wait)
    ldA(a, 1, 1, 1);
    if (2 * i + 3 < 64) stB(2 * i + 3, 1);
    if (i < 31) asm volatile("s_waitcnt vmcnt(4)" ::: "memory");
    BARX(); LGKM0(); mm(a, 1, 1); BARX();
  }
#undef BARX
#undef LGKM0

  // ---------------- fused QKV epilogue (proven in R6/R7) ----------------
  __syncthreads();  // reuse As as f32 scratch
  float* sums = (float*)&As[0][0][0];  // [4 wc][256 rows]
  if (n0 < 5120) {
    // Q or K: RoPE (pairs = adjacent lanes) + RMSNorm over 128 (wave pair wc^1)
    float ss_arr[8][4];
    const int dbase = (wc & 1) * 64;
#pragma unroll
    for (int mt = 0; mt < 8; ++mt) {
#pragma unroll
      for (int r = 0; r < 4; ++r) {
        int s = m0 + wr * 128 + mt * 16 + quad * 4 + r;
        const float* fb = freqs + (size_t)s * 128;
        float ssv = 0.0f;
#pragma unroll
        for (int nt = 0; nt < 4; ++nt) {
          int d = dbase + nt * 16 + c16;
          float v = acc[mt][nt][r];
          float p = __shfl_xor(v, 1, 64);
          f32x2 ff = *(const f32x2*)(fb + (d & ~1));
          float res = (c16 & 1) ? fmaf(v, ff.x, p * ff.y)
                                : fmaf(v, ff.x, -p * ff.y);
          acc[mt][nt][r] = res;
          ssv = fmaf(res, res, ssv);
        }
#pragma unroll
        for (int m = 1; m < 16; m <<= 1) ssv += __shfl_xor(ssv, m, 64);
        ss_arr[mt][r] = ssv;
      }
    }
    if (c16 == 0) {
#pragma unroll
      for (int mt = 0; mt < 8; ++mt)
#pragma unroll
        for (int r = 0; r < 4; ++r)
          sums[wc * 256 + wr * 128 + mt * 16 + quad * 4 + r] = ss_arr[mt][r];
    }
    __syncthreads();
    const int head_col = n0 + wc * 64;
    u16* outb = (head_col < 4096)
                    ? (qh + (size_t)(head_col >> 7) * M * 128)
                    : (khh + (size_t)((head_col - 4096) >> 7) * M * 128);
#pragma unroll
    for (int mt = 0; mt < 8; ++mt) {
#pragma unroll
      for (int r = 0; r < 4; ++r) {
        int rl = wr * 128 + mt * 16 + quad * 4 + r;
        float tot = ss_arr[mt][r] + sums[(wc ^ 1) * 256 + rl];
        float scl = rsqrtf(tot * (1.0f / 128.0f) + 1e-5f);
        int s = m0 + rl;
#pragma unroll
        for (int nt = 0; nt < 4; ++nt)
          outb[(size_t)s * 128 + dbase + nt * 16 + c16] = f2bf(acc[mt][nt][r] * scl);
      }
    }
  } else {
    // V: store transposed vt[dv][s], 4 consecutive s packed per u64 store
#pragma unroll
    for (int mt = 0; mt < 8; ++mt) {
#pragma unroll
      for (int nt = 0; nt < 4; ++nt) {
        int dv = (n0 - 5120) + wc * 64 + nt * 16 + c16;
        int s0 = m0 + wr * 128 + mt * 16 + quad * 4;
        union { u16 us[4]; u64 v; } pk;
#pragma unroll
        for (int r = 0; r < 4; ++r) pk.us[r] = f2bf(acc[mt][nt][r]);
        *(u64*)(vt + (size_t)dv * M + s0) = pk.v;
      }
    }
  }
}

// ---------------------------------------------------------------- out-proj GEMM
// Proven 128x128 async-staged kernel, f32 C output. (control)
__global__ __launch_bounds__(256, 3) void gemm_out(const u16* __restrict__ A,
                                                   const u16* __restrict__ B,
                                                   float* __restrict__ C,
                                                   int M, int N, int K) {
  __shared__ __align__(16) u16 As[128 * 64];
  __shared__ __align__(16) u16 Bs[128 * 64];
  const int tid = threadIdx.x;
  const int wave = tid >> 6, lane = tid & 63;
  const int quad = lane >> 4, c16 = lane & 15;

  const int mb = M >> 7, nb = N >> 7;
  const int per_xcd_n = nb >> 3;
  const int xcd = blockIdx.x & 7, lid = blockIdx.x >> 3;
  const int m_t = lid % mb, n_local = lid / mb;
  const int m0 = m_t * 128, n0 = (xcd * per_xcd_n + n_local) * 128;

  const int wm = (wave & 1) * 64, wn = (wave >> 1) * 64;

  f32x4 acc[4][4] = {};

  const u16* Ab = A + (size_t)m0 * K;
  const u16* Bb = B + (size_t)n0 * K;

  for (int k0 = 0; k0 < K; k0 += 64) {
    __syncthreads();
#pragma unroll
    for (int i = 0; i < 4; ++i) {
      int idx = tid + 256 * i;
      int row = idx >> 3, sg = (idx & 7) ^ (row & 7);
      async_cp16(Ab + (size_t)row * K + k0 + sg * 8, As + (size_t)idx * 8);
    }
#pragma unroll
    for (int i = 0; i < 4; ++i) {
      int idx = tid + 256 * i;
      int row = idx >> 3, sg = (idx & 7) ^ (row & 7);
      async_cp16(Bb + (size_t)row * K + k0 + sg * 8, Bs + (size_t)idx * 8);
    }
    asm volatile("s_waitcnt vmcnt(0)" ::: "memory");
    __syncthreads();

    bf16x8 af[4][2], bfr[4][2];
#pragma unroll
    for (int mt = 0; mt < 4; ++mt) {
      int row = wm + mt * 16 + c16;
#pragma unroll
      for (int c = 0; c < 2; ++c)
        af[mt][c] = *(const bf16x8*)(As + row * 64 + (((c * 4 + quad) ^ (row & 7)) * 8));
    }
#pragma unroll
    for (int nt = 0; nt < 4; ++nt) {
      int row = wn + nt * 16 + c16;
#pragma unroll
      for (int c = 0; c < 2; ++c)
        bfr[nt][c] = *(const bf16x8*)(Bs + row * 64 + (((c * 4 + quad) ^ (row & 7)) * 8));
    }
#pragma unroll
    for (int c = 0; c < 2; ++c)
#pragma unroll
      for (int mt = 0; mt < 4; ++mt)
#pragma unroll
        for (int nt = 0; nt < 4; ++nt)
          acc[mt][nt] = mfma16(af[mt][c], bfr[nt][c], acc[mt][nt]);
  }

#pragma unroll
  for (int mt = 0; mt < 4; ++mt) {
#pragma unroll
    for (int nt = 0; nt < 4; ++nt) {
#pragma unroll
      for (int r = 0; r < 4; ++r) {
        int gm = m0 + wm + mt * 16 + quad * 4 + r;
        int gn = n0 + wn + nt * 16 + c16;
        C[(size_t)gm * N + gn] = acc[mt][nt][r];
      }
    }
  }
}

// ---------------------------------------------------------------- flash attention
// R5 version: 256 blocks x 512 threads, wave-groups on tile pair {15-p, p},
// shared K/V staging stream, + slack-proportional wo->bf16 conversion tail.
#define SEQ 2048
__global__ __launch_bounds__(512, 2) void attn(const u16* __restrict__ Q,
                                               const u16* __restrict__ Kh,
                                               const u16* __restrict__ VT,
                                               u16* __restrict__ O,
                                               const float* __restrict__ wo,
                                               u16* __restrict__ wob) {
  __shared__ __align__(16) u16 Ks[2][64 * 128];
  __shared__ __align__(16) u16 Vs[2][128 * 64];
  __shared__ __align__(16) u16 Ps[8][32 * 64];
  const int tid = threadIdx.x;
  const int wave = tid >> 6, lane = tid & 63;
  const int quad = lane >> 4, c16 = lane & 15;
  const int bid = blockIdx.x;
  const int hk = bid & 7;        // kv-head pinned to one XCD's L2
  const int rest = bid >> 3;
  const int hq = rest & 3;
  const int p = rest >> 2;       // 0..7
  const int h = hk * 4 + hq;

  const int wl = wave & 3, grp = wave >> 2;
  const int qt = grp ? p : (15 - p);        // grp0 = far tile, grp1 = near tile
  const int q0w = qt * 128 + wl * 32;
  const int kend = (15 - p) * 128 + 128;    // block-uniform (covers far tile)

  const float sc = 0.12751743f;  // log2(e)/sqrt(128)
  const float B = 16.5f;
  const u16* Kb = Kh + (size_t)hk * SEQ * 128;
  const u16* Vb = VT + (size_t)hk * 128 * SEQ;

  auto stage = [&](int t0, int b) __attribute__((always_inline)) {
#pragma unroll
    for (int i = 0; i < 2; ++i) {
      int idx = tid + 512 * i;
      int row = idx >> 4, sg = (idx & 15) ^ (row & 7);
      async_cp16(Kb + (size_t)(t0 + row) * 128 + sg * 8, &Ks[b][(size_t)idx * 8]);
    }
#pragma unroll
    for (int i = 0; i < 2; ++i) {
      int idx = tid + 512 * i;
      int row = idx >> 3, sg = (idx & 7) ^ (row & 7);
      async_cp16(Vb + (size_t)row * SEQ + t0 + sg * 8, &Vs[b][(size_t)idx * 8]);
    }
  };

  bf16x8 qfr[2][4];
  const u16* qbase = Q + (size_t)h * SEQ * 128;
#pragma unroll
  for (int g = 0; g < 2; ++g)
#pragma unroll
    for (int c = 0; c < 4; ++c)
      qfr[g][c] =
          *(const bf16x8*)(qbase + (size_t)(q0w + g * 16 + c16) * 128 + c * 32 + quad * 8);

  f32x4 o_acc[2][8] = {};
  float lsum[2][4] = {};

  stage(0, 0);

#pragma unroll 1
  for (int t0 = 0; t0 < kend; t0 += 64) {
    const int cur = (t0 >> 6) & 1;
    asm volatile("s_waitcnt vmcnt(0)" ::: "memory");
    __syncthreads();
    if (t0 + 64 < kend) stage(t0 + 64, cur ^ 1);

    if (t0 < q0w + 32) {
      f32x4 sa[2][4] = {};
      __builtin_amdgcn_s_setprio(1);
#pragma unroll
      for (int ct = 0; ct < 4; ++ct) {
        int t = ct * 16 + c16;
        int tbase = t * 128;
        int tsw = t & 7;
#pragma unroll
        for (int c = 0; c < 4; ++c) {
          bf16x8 kf = *(const bf16x8*)(&Ks[cur][tbase + (((c * 4 + quad) ^ tsw) * 8)]);
          sa[0][ct] = mfma16(qfr[0][c], kf, sa[0][ct]);
          sa[1][ct] = mfma16(qfr[1][c], kf, sa[1][ct]);
        }
      }
      __builtin_amdgcn_s_setprio(0);

      const bool diag = (t0 + 64 > q0w);
      auto soft = [&](bool masked) __attribute__((always_inline)) {
#pragma unroll
        for (int g = 0; g < 2; ++g) {
#pragma unroll
          for (int r = 0; r < 4; ++r) {
            int row = g * 16 + quad * 4 + r;
            int row_q = q0w + row;
            int rbase = row * 64;
            int rsw = row & 7;
#pragma unroll
            for (int ct = 0; ct < 4; ++ct) {
              float s = sa[g][ct][r];
              float arg = fmaf(s, sc, -B);
              if (masked) {
                int t_idx = t0 + ct * 16 + c16;
                arg = (t_idx <= row_q) ? arg : -1.0e30f;
              }
              float pe = exp2f(arg);
              lsum[g][r] += pe;
              u32 pb = (__builtin_bit_cast(u32, pe) + 0x8000u) >> 16;
              Ps[wave][rbase + (((ct * 2 + (c16 >> 3)) ^ rsw) * 8) + (c16 & 7)] = (u16)pb;
            }
          }
        }
      };
      if (diag) soft(true); else soft(false);
      asm volatile("s_waitcnt lgkmcnt(0)" ::: "memory");

      __builtin_amdgcn_s_setprio(1);
#pragma unroll
      for (int tc = 0; tc < 2; ++tc) {
        bf16x8 pf[2];
#pragma unroll
        for (int g = 0; g < 2; ++g) {
          int prow = g * 16 + c16;
          pf[g] = *(const bf16x8*)(&Ps[wave][prow * 64 + (((tc * 4 + quad) ^ (prow & 7)) * 8)]);
        }
#pragma unroll
        for (int nt = 0; nt < 8; ++nt) {
          int dl = nt * 16 + c16;
          bf16x8 vf = *(const bf16x8*)(&Vs[cur][dl * 64 + (((tc * 4 + quad) ^ (dl & 7)) * 8)]);
          o_acc[0][nt] = mfma16(pf[0], vf, o_acc[0][nt]);
          o_acc[1][nt] = mfma16(pf[1], vf, o_acc[1][nt]);
        }
      }
      __builtin_amdgcn_s_setprio(0);
    }
  }

#pragma unroll
  for (int g = 0; g < 2; ++g) {
#pragma unroll
    for (int r = 0; r < 4; ++r) {
      float l = lsum[g][r];
#pragma unroll
      for (int m = 1; m < 16; m <<= 1) l += __shfl_xor(l, m, 64);
      float inv = 1.0f / l;
      int s_idx = q0w + g * 16 + quad * 4 + r;
      u16* ob = O + (size_t)s_idx * 4096 + (size_t)h * 128;
#pragma unroll
      for (int nt = 0; nt < 8; ++nt) ob[nt * 16 + c16] = f2bf(o_acc[g][nt][r] * inv);
    }
  }

  // ---- wo->bf16 conversion tail, weighted by p (slack-proportional) ----
  {
    const int UNIT = 2341;                       // 896*2341 >= 2097152
    const int N8 = 2097152;                      // 4096*4096/8
    int su = 16 * p * (p - 1) + (bid & 31) * p;  // prefix units
    int i = su * UNIT + tid;
    int end = su * UNIT + p * UNIT;
    if (end > N8) end = N8;
    for (; i < end; i += 512) {
      const float4* src = (const float4*)(wo + (size_t)i * 8);
      float4 a = src[0], b = src[1];
      union { u16 us[8]; u32x4 v; } o;
      o.us[0] = f2bf(a.x); o.us[1] = f2bf(a.y); o.us[2] = f2bf(a.z); o.us[3] = f2bf(a.w);
      o.us[4] = f2bf(b.x); o.us[5] = f2bf(b.y); o.us[6] = f2bf(b.z); o.us[7] = f2bf(b.w);
      *(u32x4*)(wob + (size_t)i * 8) = o.v;
    }
  }
}

// ---------------------------------------------------------------- launch
extern "C" void kernel_launch(void* const* d_in, const int* in_sizes, int n_in,
                              void* d_out, int out_size, void* d_ws, size_t ws_size,
                              hipStream_t stream) {
  const float* x  = (const float*)d_in[0];
  const float* wq = (const float*)d_in[1];
  const float* wk = (const float*)d_in[2];
  const float* wv = (const float*)d_in[3];
  const float* wo = (const float*)d_in[4];
  const float* fr = (const float*)d_in[5];
  float* out = (float*)d_out;

  const size_t S = 2048, D = 4096, KV = 1024, NQKV = D + 2 * KV;  // 6144
  u16* p = (u16*)d_ws;
  u16* xb   = p; p += S * D;
  u16* wqkv = p; p += NQKV * D;
  u16* qh   = p; p += S * D;
  u16* khh  = p; p += S * KV;
  u16* vt   = p; p += KV * S;
  u16* ob   = p; p += S * D;
  u16* wob = wqkv;  // wqkv dead after QKV gemm; attn writes it, out-proj reads it

  // fused convert of x, wq, wk, wv (one launch)
  cvt4<<<dim3(2048), dim3(256), 0, stream>>>(x, wq, wk, wv, xb, wqkv);

  // fused QKV GEMM (256x256 8-phase counted-vmcnt) + RoPE/RMSNorm/V-transpose
  gemm256<<<dim3((S / 256) * (NQKV / 256)), dim3(512), 0, stream>>>(
      xb, wqkv, (int)S, (int)NQKV, (int)D, qh, khh, vt, fr);

  // attention + slack-scheduled wo conversion
  attn<<<dim3(256), dim3(512), 0, stream>>>(qh, khh, vt, ob, wo, wob);

  gemm_out<<<dim3((S / 128) * (D / 128)), dim3(256), 0, stream>>>(
      ob, wob, out, (int)S, (int)D, (int)D);
}